// Round 1
// baseline (2053.849 us; speedup 1.0000x reference)
//
#include <hip/hip_runtime.h>

typedef unsigned short u16;
typedef short bf16x8 __attribute__((ext_vector_type(8)));
typedef float f32x4 __attribute__((ext_vector_type(4)));

typedef const __attribute__((address_space(1))) void* gaddr_t;
typedef __attribute__((address_space(3))) void* laddr_t;

__device__ __forceinline__ u16 f2b(float f){
  unsigned u = __float_as_uint(f);
  u = (u + 0x7fffu + ((u >> 16) & 1u)) >> 16;
  return (u16)u;
}
__device__ __forceinline__ float b2f(u16 h){
  return __uint_as_float(((unsigned)h) << 16);
}
__device__ __forceinline__ float2 cmul(float2 a, float2 b){
  return make_float2(a.x*b.x - a.y*b.y, a.x*b.y + a.y*b.x);
}

// ---------------- casts ----------------
__global__ void cast_f32_bf16(const float* __restrict__ s, u16* __restrict__ d, int n4){
  int i = blockIdx.x*blockDim.x + threadIdx.x;
  int st = gridDim.x*blockDim.x;
  for (int idx = i; idx < n4; idx += st){
    float4 v = ((const float4*)s)[idx];
    ushort4 o; o.x=f2b(v.x); o.y=f2b(v.y); o.z=f2b(v.z); o.w=f2b(v.w);
    ((ushort4*)d)[idx] = o;
  }
}

// ---------------- inversion: blocked Gauss-Jordan on [V | I] ----------------
__global__ void inv_init(const float* __restrict__ vr, const float* __restrict__ vi,
                         float2* __restrict__ aug, float2* __restrict__ prow){
  int idx = blockIdx.x*256 + threadIdx.x;   // 512*1024
  int r = idx >> 10, c = idx & 1023;
  float2 v;
  if (c < 512) v = make_float2(vr[r*512+c], vi[r*512+c]);
  else         v = make_float2((c-512)==r ? 1.f : 0.f, 0.f);
  aug[idx] = v;
  if (r < 32 && c >= 32) prow[idx] = v;     // pivot-row copy for step bs=0
}

// invert the 32x32 diagonal block (1 wave, in-block partial pivoting)
__global__ __launch_bounds__(64) void inv_panel(const float2* __restrict__ aug, int bs,
                                                float2* __restrict__ binv){
  __shared__ float2 T[32][66];
  const int lane = threadIdx.x;
  for (int r = 0; r < 32; ++r){
    float2 v;
    if (lane < 32) v = aug[(size_t)(bs+r)*1024 + bs + lane];
    else           v = make_float2((lane-32)==r ? 1.f : 0.f, 0.f);
    T[r][lane] = v;
  }
  __syncthreads();
  for (int k = 0; k < 32; ++k){
    float mag = -1.f;
    if (lane >= k && lane < 32){
      float2 vv = T[lane][k];
      mag = vv.x*vv.x + vv.y*vv.y;
    }
    int best = lane;
    #pragma unroll
    for (int off = 1; off < 32; off <<= 1){
      float om = __shfl_xor(mag, off);
      int ob  = __shfl_xor(best, off);
      if (om > mag || (om == mag && ob < best)){ mag = om; best = ob; }
    }
    int p = __shfl(best, 0);
    float2 pv = T[p][k];
    float dinv = 1.f / (pv.x*pv.x + pv.y*pv.y);
    float2 pinv = make_float2(pv.x*dinv, -pv.y*dinv);
    float2 rk = T[k][lane];
    float2 rp = T[p][lane];
    float2 nk = cmul(rp, pinv);
    T[k][lane] = nk;
    if (p != k) T[p][lane] = rk;
    for (int r = 0; r < 32; ++r){
      if (r == k) continue;
      float2 f = T[r][k];
      float2 cell = T[r][lane];
      cell.x -= f.x*nk.x - f.y*nk.y;
      cell.y -= f.x*nk.y + f.y*nk.x;
      T[r][lane] = cell;
    }
  }
  for (int idx = lane; idx < 1024; idx += 64)
    binv[idx] = T[idx >> 5][32 + (idx & 31)];
}

// trailing update: piv rows <- Binv*Prow ; others -= P * (Binv*Prow)
__global__ __launch_bounds__(256) void inv_update(float2* __restrict__ aug, int bs,
    const float2* __restrict__ prow, float2* __restrict__ prow_next,
    const float2* __restrict__ binv){
  __shared__ float2 Bi[32][33];
  __shared__ float2 T1[32][33];
  __shared__ float2 Pc[128][33];
  const int tid = threadIdx.x;
  const int c0 = bs + 32 + blockIdx.x*32;
  const int r0 = blockIdx.y*128;
  for (int idx = tid; idx < 1024; idx += 256) Bi[idx>>5][idx&31] = binv[idx];
  for (int idx = tid; idx < 128*32; idx += 256){
    int rr = idx>>5, j = idx&31;
    Pc[rr][j] = aug[(size_t)(r0+rr)*1024 + bs + j];
  }
  __syncthreads();
  for (int idx = tid; idx < 1024; idx += 256){
    int j = idx>>5, cc = idx&31;
    float2 acc = make_float2(0.f, 0.f);
    for (int kk = 0; kk < 32; ++kk){
      float2 bv = Bi[j][kk];
      float2 sv = prow[(size_t)kk*1024 + c0 + cc];
      acc.x += bv.x*sv.x - bv.y*sv.y;
      acc.y += bv.x*sv.y + bv.y*sv.x;
    }
    T1[j][cc] = acc;
  }
  __syncthreads();
  for (int idx = tid; idx < 128*32; idx += 256){
    int rr = idx>>5, cc = idx&31;
    int r = r0+rr, c = c0+cc;
    float2 nv;
    if (r >= bs && r < bs+32){
      nv = T1[r-bs][cc];
    } else {
      nv = aug[(size_t)r*1024 + c];
      #pragma unroll 8
      for (int j = 0; j < 32; ++j){
        float2 pq = Pc[rr][j], t = T1[j][cc];
        nv.x -= pq.x*t.x - pq.y*t.y;
        nv.y -= pq.x*t.y + pq.y*t.x;
      }
    }
    aug[(size_t)r*1024 + c] = nv;
    int rn = r - (bs+32);
    if (rn >= 0 && rn < 32) prow_next[(size_t)rn*1024 + c] = nv;
  }
}

// ---------------- small builds ----------------
// Minv rows interleaved: row 2m = [Ar[m,:], -Ai[m,:]], row 2m+1 = [Ai[m,:], Ar[m,:]]
__global__ void build_minv(const float2* __restrict__ aug, u16* __restrict__ Mi){
  int idx = blockIdx.x*256 + threadIdx.x;     // 1024*1024
  int row = idx >> 10, col = idx & 1023;
  int m = row >> 1, irow = row & 1;
  int k = col & 511, icol = col >> 9;
  float2 a = aug[(size_t)m*1024 + 512 + k];   // Vinv[m][k]
  float v;
  if (!irow) v = icol ? -a.y : a.x;
  else       v = icol ?  a.x : a.y;
  Mi[idx] = f2b(v);
}
// Mv4: row m, cols interleaved: 2n = Vr[m,n], 2n+1 = -Vi[m,n]
__global__ void build_mv4(const float* __restrict__ vr, const float* __restrict__ vi,
                          u16* __restrict__ Mv){
  int idx = blockIdx.x*256 + threadIdx.x;     // 512*1024
  int m = idx >> 10, col = idx & 1023;
  int n = col >> 1;
  float v = (col & 1) ? -vi[m*512+n] : vr[m*512+n];
  Mv[idx] = f2b(v);
}
__global__ void fill_h0(const float* __restrict__ lhr, const float* __restrict__ lhi,
                        u16* __restrict__ xroll){
  int idx = blockIdx.x*256 + threadIdx.x;     // 4*1024
  int b = idx >> 10, c = idx & 1023;
  float v = (c < 512) ? lhr[c] : lhi[c-512];
  xroll[(size_t)b*4096*1024 + c] = f2b(v);
}

// ---------------- GEMM: 128x128 tile, mfma 16x16x32 bf16, B is (N,K) row-major ----------------
enum { EPI_BF16 = 0, EPI_A = 1, EPI_X = 2, EPI_ADDXC = 3, EPI_OUTF32 = 4 };

template<int EPI>
__global__ __launch_bounds__(256) void gemm128(
    const u16* __restrict__ A, const u16* __restrict__ B,
    int M, int N, int K,
    void* __restrict__ C, void* __restrict__ aux0, void* __restrict__ aux1){
  __shared__ u16 As[128*32];
  __shared__ u16 Bs[128*32];
  const int tid = threadIdx.x;
  const int lane = tid & 63;
  const int w = tid >> 6, wr = w >> 1, wc = w & 1;
  const int fr = lane & 15, kg = lane >> 4;
  const size_t arow0 = (size_t)blockIdx.x * 128;
  const size_t brow0 = (size_t)blockIdx.y * 128;
  f32x4 acc[4][4] = {};
  const int nk = K >> 5;
  for (int kt = 0; kt < nk; ++kt){
    const int kofs = kt << 5;
    __syncthreads();
    #pragma unroll
    for (int half = 0; half < 2; ++half){
      const int id = tid + half*256;
      const u16* ag = A + (arow0 + (id>>2))*K + kofs + (id&3)*8;
      __builtin_amdgcn_global_load_lds((gaddr_t)ag, (laddr_t)(As + (id & ~63)*8), 16, 0, 0);
      const u16* bg = B + (brow0 + (id>>2))*K + kofs + (id&3)*8;
      __builtin_amdgcn_global_load_lds((gaddr_t)bg, (laddr_t)(Bs + (id & ~63)*8), 16, 0, 0);
    }
    __syncthreads();
    bf16x8 af[4], bv[4];
    #pragma unroll
    for (int m = 0; m < 4; ++m){
      int r = wr*64 + m*16 + fr;
      af[m] = *(const bf16x8*)&As[r*32 + kg*8];
    }
    #pragma unroll
    for (int n = 0; n < 4; ++n){
      int r = wc*64 + n*16 + fr;
      bv[n] = *(const bf16x8*)&Bs[r*32 + kg*8];
    }
    #pragma unroll
    for (int m = 0; m < 4; ++m)
      #pragma unroll
      for (int n = 0; n < 4; ++n)
        acc[m][n] = __builtin_amdgcn_mfma_f32_16x16x32_bf16(af[m], bv[n], acc[m][n], 0, 0, 0);
  }
  const int rbase = wr*64 + (lane>>4)*4;
  const int cbase = wc*64 + fr;
  #pragma unroll
  for (int m = 0; m < 4; ++m){
    #pragma unroll
    for (int n = 0; n < 4; ++n){
      #pragma unroll
      for (int j = 0; j < 4; ++j){
        float v = acc[m][n][j];
        size_t gr = arow0 + rbase + m*16 + j;
        int gc = (int)brow0 + cbase + n*16;
        if constexpr (EPI == EPI_BF16){
          ((u16*)C)[gr*(size_t)N + gc] = f2b(v);
        } else if constexpr (EPI == EPI_OUTF32){
          ((float*)C)[gr*(size_t)N + gc] = v;
        } else if constexpr (EPI == EPI_ADDXC){
          float xc = b2f(((const u16*)aux0)[gr*512 + gc]);
          ((u16*)C)[gr*512 + gc] = f2b(v + xc);
        } else {
          float pv = __shfl_xor(v, 1);
          int odd = lane & 1;
          float re = odd ? pv : v;
          float im = odd ? v : pv;
          float m2 = re*re + im*im;
          int mh = gc >> 1;
          if constexpr (EPI == EPI_A){
            // a = a2 * sqrt(m)/(1+m)   [sigmoid(log m) = m/(1+m)]
            float sc = m2 > 0.f ? sqrtf(m2)/(1.f + m2) : 0.f;
            if (!odd){
              unsigned pk = (unsigned)f2b(re*sc) | ((unsigned)f2b(im*sc) << 16);
              ((unsigned*)aux0)[gr*512 + mh] = pk;   // interleaved complex a
            }
          } else { // EPI_X : xc = x2 * sqrt(m)
            float sc = sqrtf(m2);
            u16 ob = f2b(v * sc);
            if (!odd) ((u16*)aux0)[gr*512 + mh] = ob;          // xc_re
            int t = (int)(gr & 4095);
            if (t != 4095)                                      // x_roll[t+1] = xc[t]
              ((u16*)aux1)[(gr+1)*1024 + (odd ? 512 + mh : mh)] = ob;
          }
        }
      }
    }
  }
}

// ---------------- scan: s_t = a_t*(s_{t-1}+u_t), chunked 3-phase ----------------
// 64 chunks of 64 along L; a,u,s stored as interleaved bf16 complex (one dword each)
__global__ void scan_p1(const unsigned* __restrict__ aint, const unsigned* __restrict__ uint_,
                        float4* __restrict__ agg){
  int idx = blockIdx.x*256 + threadIdx.x;   // 4*64*512 = 131072
  int m = idx & 511, chunk = (idx >> 9) & 63, b = idx >> 15;
  size_t row = (size_t)b*4096 + chunk*64;
  float px=1.f, py=0.f, sx=0.f, sy=0.f;
  for (int i = 0; i < 64; ++i, ++row){
    unsigned av = aint[row*512 + m];
    unsigned uv = uint_[row*512 + m];
    float ar = b2f((u16)av), ai = b2f((u16)(av>>16));
    float ur = b2f((u16)uv), ui = b2f((u16)(uv>>16));
    float tx = sx + ur, ty = sy + ui;
    sx = ar*tx - ai*ty; sy = ar*ty + ai*tx;
    float np = px*ar - py*ai; py = px*ai + py*ar; px = np;
  }
  agg[((size_t)(b*512+m))*64 + chunk] = make_float4(px,py,sx,sy);
}
__global__ void scan_p2(const float4* __restrict__ agg, float2* __restrict__ carry){
  int seq = blockIdx.x*256 + threadIdx.x;   // 2048
  float sx = 0.f, sy = 0.f;
  for (int c = 0; c < 64; ++c){
    carry[(size_t)seq*64 + c] = make_float2(sx, sy);
    float4 g = agg[(size_t)seq*64 + c];
    float nx = g.x*sx - g.y*sy + g.z;
    sy = g.x*sy + g.y*sx + g.w; sx = nx;
  }
}
__global__ void scan_p3(const unsigned* __restrict__ aint, const unsigned* __restrict__ uint_,
                        const float2* __restrict__ carry, unsigned* __restrict__ sout){
  int idx = blockIdx.x*256 + threadIdx.x;
  int m = idx & 511, chunk = (idx >> 9) & 63, b = idx >> 15;
  size_t row = (size_t)b*4096 + chunk*64;
  float2 c0 = carry[((size_t)(b*512+m))*64 + chunk];
  float sx = c0.x, sy = c0.y;
  for (int i = 0; i < 64; ++i, ++row){
    unsigned av = aint[row*512 + m];
    unsigned uv = uint_[row*512 + m];
    float ar = b2f((u16)av), ai = b2f((u16)(av>>16));
    float ur = b2f((u16)uv), ui = b2f((u16)(uv>>16));
    float tx = sx + ur, ty = sy + ui;
    sx = ar*tx - ai*ty; sy = ar*ty + ai*tx;
    sout[row*512 + m] = (unsigned)f2b(sx) | ((unsigned)f2b(sy) << 16);
  }
}

// ---------------- host ----------------
extern "C" void kernel_launch(void* const* d_in, const int* in_sizes, int n_in,
                              void* d_out, int out_size, void* d_ws, size_t ws_size,
                              hipStream_t stream){
  (void)in_sizes; (void)n_in; (void)out_size; (void)ws_size;
  const float* x   = (const float*)d_in[0];
  const float* wa  = (const float*)d_in[1];
  const float* wx  = (const float*)d_in[2];
  const float* wo  = (const float*)d_in[3];
  const float* vr  = (const float*)d_in[4];
  const float* vi  = (const float*)d_in[5];
  const float* lhr = (const float*)d_in[6];
  const float* lhi = (const float*)d_in[7];

  char* ws = (char*)d_ws;
  const size_t SB = 16384ull*1024*2;      // 33.5 MB
  const size_t HB = SB/2;
  u16* Xb    = (u16*)(ws);                // [0,SB) ; later reused as U
  unsigned* AINT = (unsigned*)(ws + SB);  // [SB,2SB) interleaved a ; first half later HRE
  u16* XROLL = (u16*)(ws + 2*SB);         // [2SB,3SB) ; later reused as S
  u16* XCRE  = (u16*)(ws + 3*SB);         // [3SB,3SB+HB)
  char* p = ws + 3*SB + HB;
  u16* WAb   = (u16*)p; p += 2097152;
  u16* WXb   = (u16*)p; p += 2097152;
  u16* MINV  = (u16*)p; p += 2097152;
  u16* MV4   = (u16*)p; p += 1048576;
  u16* WOUTb = (u16*)p; p += 1048576;
  float2* AUG   = (float2*)p; p += 4194304;
  float2* PROWA = (float2*)p; p += 262144;
  float2* PROWB = (float2*)p; p += 262144;
  float2* BINV  = (float2*)p; p += 8192;
  float4* AGG   = (float4*)p; p += 2048ull*64*16;
  float2* CARRY = (float2*)p; p += 2048ull*64*8;
  u16* U   = Xb;                 // G3 output (interleaved complex, viewed as u32)
  u16* S   = XROLL;              // scan output (interleaved complex)
  u16* HRE = (u16*)AINT;         // G4 output

  cast_f32_bf16<<<2048,256,0,stream>>>(x,  Xb,    16777216/4);
  cast_f32_bf16<<<512, 256,0,stream>>>(wa, WAb,   1048576/4);
  cast_f32_bf16<<<512, 256,0,stream>>>(wx, WXb,   1048576/4);
  cast_f32_bf16<<<256, 256,0,stream>>>(wo, WOUTb, 524288/4);

  inv_init<<<2048,256,0,stream>>>(vr, vi, AUG, PROWA);
  float2* pr = PROWA; float2* prn = PROWB;
  for (int bs = 0; bs < 512; bs += 32){
    inv_panel<<<1,64,0,stream>>>(AUG, bs, BINV);
    inv_update<<<dim3((992-bs)/32, 4),256,0,stream>>>(AUG, bs, pr, prn, BINV);
    float2* t = pr; pr = prn; prn = t;
  }
  build_minv<<<4096,256,0,stream>>>(AUG, MINV);
  build_mv4<<<2048,256,0,stream>>>(vr, vi, MV4);

  gemm128<EPI_A><<<dim3(128,8),256,0,stream>>>(Xb, WAb, 16384,1024,1024, nullptr, (void*)AINT, nullptr);
  gemm128<EPI_X><<<dim3(128,8),256,0,stream>>>(Xb, WXb, 16384,1024,1024, nullptr, (void*)XCRE, (void*)XROLL);
  fill_h0<<<16,256,0,stream>>>(lhr, lhi, XROLL);
  gemm128<EPI_BF16><<<dim3(128,8),256,0,stream>>>(XROLL, MINV, 16384,1024,1024, (void*)U, nullptr, nullptr);

  scan_p1<<<512,256,0,stream>>>((const unsigned*)AINT, (const unsigned*)U, AGG);
  scan_p2<<<8,256,0,stream>>>(AGG, CARRY);
  scan_p3<<<512,256,0,stream>>>((const unsigned*)AINT, (const unsigned*)U, CARRY, (unsigned*)S);

  gemm128<EPI_ADDXC><<<dim3(128,4),256,0,stream>>>(S, MV4, 16384,512,1024, (void*)HRE, (void*)XCRE, nullptr);
  gemm128<EPI_OUTF32><<<dim3(128,8),256,0,stream>>>(HRE, WOUTb, 16384,1024,512, d_out, nullptr, nullptr);
}

// Round 2
// 1463.199 us; speedup vs baseline: 1.4037x; 1.4037x over previous
//
#include <hip/hip_runtime.h>

typedef unsigned short u16;
typedef short bf16x8 __attribute__((ext_vector_type(8)));
typedef float f32x4 __attribute__((ext_vector_type(4)));

typedef const __attribute__((address_space(1))) void* gaddr_t;
typedef __attribute__((address_space(3))) void* laddr_t;

__device__ __forceinline__ u16 f2b(float f){
  unsigned u = __float_as_uint(f);
  u = (u + 0x7fffu + ((u >> 16) & 1u)) >> 16;
  return (u16)u;
}
__device__ __forceinline__ float b2f(u16 h){
  return __uint_as_float(((unsigned)h) << 16);
}
__device__ __forceinline__ float2 cmul(float2 a, float2 b){
  return make_float2(a.x*b.x - a.y*b.y, a.x*b.y + a.y*b.x);
}

// ---------------- casts ----------------
__global__ void cast_f32_bf16(const float* __restrict__ s, u16* __restrict__ d, int n4){
  int i = blockIdx.x*blockDim.x + threadIdx.x;
  int st = gridDim.x*blockDim.x;
  for (int idx = i; idx < n4; idx += st){
    float4 v = ((const float4*)s)[idx];
    ushort4 o; o.x=f2b(v.x); o.y=f2b(v.y); o.z=f2b(v.z); o.w=f2b(v.w);
    ((ushort4*)d)[idx] = o;
  }
}

// ---------------- inversion: blocked Gauss-Jordan on [V | I] ----------------
__global__ void inv_init(const float* __restrict__ vr, const float* __restrict__ vi,
                         float2* __restrict__ aug, float2* __restrict__ prow){
  int idx = blockIdx.x*256 + threadIdx.x;   // 512*1024
  int r = idx >> 10, c = idx & 1023;
  float2 v;
  if (c < 512) v = make_float2(vr[r*512+c], vi[r*512+c]);
  else         v = make_float2((c-512)==r ? 1.f : 0.f, 0.f);
  aug[idx] = v;
  if (r < 32 && c >= 32) prow[idx] = v;     // pivot-row copy for step bs=0
}

// invert the 32x32 diagonal block — 256 threads, latency-tolerant
__global__ __launch_bounds__(256) void inv_panel(const float2* __restrict__ aug, int bs,
                                                 float2* __restrict__ binv){
  __shared__ float2 T[32][66];
  __shared__ float2 fcol[32];
  const int tid = threadIdx.x;
  for (int i = tid; i < 2048; i += 256){
    int r = i >> 6, c = i & 63;
    float2 v;
    if (c < 32) v = aug[(size_t)(bs+r)*1024 + bs + c];
    else        v = make_float2((c-32)==r ? 1.f : 0.f, 0.f);
    T[r][c] = v;
  }
  __syncthreads();
  for (int k = 0; k < 32; ++k){
    if (tid < 64){
      const int lane = tid;
      float2 colv = make_float2(0.f, 0.f);
      float mag = -1.f;
      if (lane < 32){
        colv = T[lane][k];
        if (lane >= k) mag = colv.x*colv.x + colv.y*colv.y;
      }
      int best = lane;
      #pragma unroll
      for (int off = 1; off < 32; off <<= 1){
        float om = __shfl_xor(mag, off);
        int ob  = __shfl_xor(best, off);
        if (om > mag || (om == mag && ob < best)){ mag = om; best = ob; }
      }
      const int p = __shfl(best, 0);
      float pvx = __shfl(colv.x, p), pvy = __shfl(colv.y, p);
      float dinv = 1.f / (pvx*pvx + pvy*pvy);
      float2 pinv = make_float2(pvx*dinv, -pvy*dinv);
      // row swap + scale (lane = column 0..63)
      float2 rk = T[k][lane];
      float2 rp = T[p][lane];
      float2 nk = cmul(rp, pinv);
      T[k][lane] = nk;
      if (p != k) T[p][lane] = rk;
      // fcol[r] = post-swap T[r][k] (r==p gets old T[k][k])
      if (lane < 32){
        float2 f = colv;
        float okx = __shfl(colv.x, k), oky = __shfl(colv.y, k);
        if (lane == p){ f.x = okx; f.y = oky; }
        fcol[lane] = f;
      }
    }
    __syncthreads();
    #pragma unroll
    for (int i = 0; i < 8; ++i){
      int idx = tid + i*256;
      int r = idx >> 6, c = idx & 63;
      if (r != k){
        float2 f = fcol[r], nk = T[k][c];
        float2 cell = T[r][c];
        cell.x -= f.x*nk.x - f.y*nk.y;
        cell.y -= f.x*nk.y + f.y*nk.x;
        T[r][c] = cell;
      }
    }
    __syncthreads();
  }
  for (int i = tid; i < 1024; i += 256)
    binv[i] = T[i>>5][32+(i&31)];
}

// trailing update: piv rows <- Binv*Prow ; others -= P * (Binv*Prow)
__global__ __launch_bounds__(256) void inv_update(float2* __restrict__ aug, int bs,
    const float2* __restrict__ prow, float2* __restrict__ prow_next,
    const float2* __restrict__ binv){
  __shared__ float2 Bi[32][33];
  __shared__ float2 T1[32][33];
  __shared__ float2 Pc[128][33];
  const int tid = threadIdx.x;
  const int c0 = bs + 32 + blockIdx.x*32;
  const int r0 = blockIdx.y*128;
  for (int idx = tid; idx < 1024; idx += 256) Bi[idx>>5][idx&31] = binv[idx];
  for (int idx = tid; idx < 128*32; idx += 256){
    int rr = idx>>5, j = idx&31;
    Pc[rr][j] = aug[(size_t)(r0+rr)*1024 + bs + j];
  }
  __syncthreads();
  for (int idx = tid; idx < 1024; idx += 256){
    int j = idx>>5, cc = idx&31;
    float2 acc = make_float2(0.f, 0.f);
    for (int kk = 0; kk < 32; ++kk){
      float2 bv = Bi[j][kk];
      float2 sv = prow[(size_t)kk*1024 + c0 + cc];
      acc.x += bv.x*sv.x - bv.y*sv.y;
      acc.y += bv.x*sv.y + bv.y*sv.x;
    }
    T1[j][cc] = acc;
  }
  __syncthreads();
  for (int idx = tid; idx < 128*32; idx += 256){
    int rr = idx>>5, cc = idx&31;
    int r = r0+rr, c = c0+cc;
    float2 nv;
    if (r >= bs && r < bs+32){
      nv = T1[r-bs][cc];
    } else {
      nv = aug[(size_t)r*1024 + c];
      #pragma unroll 8
      for (int j = 0; j < 32; ++j){
        float2 pq = Pc[rr][j], t = T1[j][cc];
        nv.x -= pq.x*t.x - pq.y*t.y;
        nv.y -= pq.x*t.y + pq.y*t.x;
      }
    }
    aug[(size_t)r*1024 + c] = nv;
    int rn = r - (bs+32);
    if (rn >= 0 && rn < 32) prow_next[(size_t)rn*1024 + c] = nv;
  }
}

// ---------------- small builds ----------------
__global__ void build_minv(const float2* __restrict__ aug, u16* __restrict__ Mi){
  int idx = blockIdx.x*256 + threadIdx.x;     // 1024*1024
  int row = idx >> 10, col = idx & 1023;
  int m = row >> 1, irow = row & 1;
  int k = col & 511, icol = col >> 9;
  float2 a = aug[(size_t)m*1024 + 512 + k];   // Vinv[m][k]
  float v;
  if (!irow) v = icol ? -a.y : a.x;
  else       v = icol ?  a.x : a.y;
  Mi[idx] = f2b(v);
}
__global__ void build_mv4(const float* __restrict__ vr, const float* __restrict__ vi,
                          u16* __restrict__ Mv){
  int idx = blockIdx.x*256 + threadIdx.x;     // 512*1024
  int m = idx >> 10, col = idx & 1023;
  int n = col >> 1;
  float v = (col & 1) ? -vi[m*512+n] : vr[m*512+n];
  Mv[idx] = f2b(v);
}
__global__ void fill_h0(const float* __restrict__ lhr, const float* __restrict__ lhi,
                        u16* __restrict__ xroll){
  int idx = blockIdx.x*256 + threadIdx.x;     // 4*1024
  int b = idx >> 10, c = idx & 1023;
  float v = (c < 512) ? lhr[c] : lhi[c-512];
  xroll[(size_t)b*4096*1024 + c] = f2b(v);
}

// ---------------- GEMM: 128x128 tile, dbuf 2-phase, XOR-swizzled LDS ----------------
enum { EPI_BF16 = 0, EPI_A = 1, EPI_X = 2, EPI_ADDXC = 3, EPI_OUTF32 = 4 };

template<int EPI>
__global__ __launch_bounds__(256) void gemm128(
    const u16* __restrict__ A, const u16* __restrict__ B,
    int M, int N, int K,
    void* __restrict__ C, void* __restrict__ aux0, void* __restrict__ aux1){
  __shared__ u16 As[2][4096];
  __shared__ u16 Bs[2][4096];
  const int tid = threadIdx.x;
  const int lane = tid & 63;
  const int w = tid >> 6, wr = w >> 1, wc = w & 1;
  const int fr = lane & 15, kg = lane >> 4;
  const size_t arow0 = (size_t)blockIdx.x * 128;
  const size_t brow0 = (size_t)blockIdx.y * 128;
  f32x4 acc[4][4] = {};
  const int nk = K >> 5;

  auto STAGE = [&](int buf, int kofs){
    #pragma unroll
    for (int half = 0; half < 2; ++half){
      const int id = tid + half*256;
      const int row = id >> 2;
      const int ch  = (id & 3) ^ ((row >> 1) & 3);   // pre-swizzled source
      const u16* ag = A + (arow0 + row)*K + kofs + ch*8;
      __builtin_amdgcn_global_load_lds((gaddr_t)ag, (laddr_t)(As[buf] + (id & ~63)*8), 16, 0, 0);
      const u16* bg = B + (brow0 + row)*K + kofs + ch*8;
      __builtin_amdgcn_global_load_lds((gaddr_t)bg, (laddr_t)(Bs[buf] + (id & ~63)*8), 16, 0, 0);
    }
  };

  STAGE(0, 0);
  __syncthreads();
  int cur = 0;
  for (int kt = 0; kt < nk; ++kt){
    if (kt + 1 < nk) STAGE(cur ^ 1, (kt + 1) << 5);
    bf16x8 af[4], bv[4];
    #pragma unroll
    for (int m = 0; m < 4; ++m){
      int r = wr*64 + m*16 + fr;
      int pos = kg ^ ((r >> 1) & 3);                 // swizzled read
      af[m] = *(const bf16x8*)&As[cur][r*32 + pos*8];
    }
    #pragma unroll
    for (int n = 0; n < 4; ++n){
      int r = wc*64 + n*16 + fr;
      int pos = kg ^ ((r >> 1) & 3);
      bv[n] = *(const bf16x8*)&Bs[cur][r*32 + pos*8];
    }
    #pragma unroll
    for (int m = 0; m < 4; ++m)
      #pragma unroll
      for (int n = 0; n < 4; ++n)
        acc[m][n] = __builtin_amdgcn_mfma_f32_16x16x32_bf16(af[m], bv[n], acc[m][n], 0, 0, 0);
    __syncthreads();
    cur ^= 1;
  }

  const int rbase = wr*64 + (lane>>4)*4;
  const int cbase = wc*64 + fr;
  #pragma unroll
  for (int m = 0; m < 4; ++m){
    #pragma unroll
    for (int n = 0; n < 4; ++n){
      #pragma unroll
      for (int j = 0; j < 4; ++j){
        float v = acc[m][n][j];
        size_t gr = arow0 + rbase + m*16 + j;
        int gc = (int)brow0 + cbase + n*16;
        if constexpr (EPI == EPI_BF16){
          ((u16*)C)[gr*(size_t)N + gc] = f2b(v);
        } else if constexpr (EPI == EPI_OUTF32){
          ((float*)C)[gr*(size_t)N + gc] = v;
        } else if constexpr (EPI == EPI_ADDXC){
          float xc = b2f(((const u16*)aux0)[gr*512 + gc]);
          ((u16*)C)[gr*512 + gc] = f2b(v + xc);
        } else {
          float pv = __shfl_xor(v, 1);
          int odd = lane & 1;
          float re = odd ? pv : v;
          float im = odd ? v : pv;
          float m2 = re*re + im*im;
          int mh = gc >> 1;
          if constexpr (EPI == EPI_A){
            float sc = m2 > 0.f ? sqrtf(m2)/(1.f + m2) : 0.f;   // sigmoid(log m) = m/(1+m)
            if (!odd){
              unsigned pk = (unsigned)f2b(re*sc) | ((unsigned)f2b(im*sc) << 16);
              ((unsigned*)aux0)[gr*512 + mh] = pk;
            }
          } else { // EPI_X : xc = x2 * sqrt(m)
            float sc = sqrtf(m2);
            u16 ob = f2b(v * sc);
            if (!odd) ((u16*)aux0)[gr*512 + mh] = ob;
            int t = (int)(gr & 4095);
            if (t != 4095)
              ((u16*)aux1)[(gr+1)*1024 + (odd ? 512 + mh : mh)] = ob;
          }
        }
      }
    }
  }
}

// ---------------- scan: s_t = a_t*(s_{t-1}+u_t), chunked 3-phase ----------------
__global__ void scan_p1(const unsigned* __restrict__ aint, const unsigned* __restrict__ uint_,
                        float4* __restrict__ agg){
  int idx = blockIdx.x*256 + threadIdx.x;   // 4*64*512 = 131072
  int m = idx & 511, chunk = (idx >> 9) & 63, b = idx >> 15;
  size_t row = (size_t)b*4096 + chunk*64;
  float px=1.f, py=0.f, sx=0.f, sy=0.f;
  for (int i = 0; i < 64; ++i, ++row){
    unsigned av = aint[row*512 + m];
    unsigned uv = uint_[row*512 + m];
    float ar = b2f((u16)av), ai = b2f((u16)(av>>16));
    float ur = b2f((u16)uv), ui = b2f((u16)(uv>>16));
    float tx = sx + ur, ty = sy + ui;
    sx = ar*tx - ai*ty; sy = ar*ty + ai*tx;
    float np = px*ar - py*ai; py = px*ai + py*ar; px = np;
  }
  agg[((size_t)(b*512+m))*64 + chunk] = make_float4(px,py,sx,sy);
}
__global__ void scan_p2(const float4* __restrict__ agg, float2* __restrict__ carry){
  int seq = blockIdx.x*256 + threadIdx.x;   // 2048
  float sx = 0.f, sy = 0.f;
  for (int c = 0; c < 64; ++c){
    carry[(size_t)seq*64 + c] = make_float2(sx, sy);
    float4 g = agg[(size_t)seq*64 + c];
    float nx = g.x*sx - g.y*sy + g.z;
    sy = g.x*sy + g.y*sx + g.w; sx = nx;
  }
}
__global__ void scan_p3(const unsigned* __restrict__ aint, const unsigned* __restrict__ uint_,
                        const float2* __restrict__ carry, unsigned* __restrict__ sout){
  int idx = blockIdx.x*256 + threadIdx.x;
  int m = idx & 511, chunk = (idx >> 9) & 63, b = idx >> 15;
  size_t row = (size_t)b*4096 + chunk*64;
  float2 c0 = carry[((size_t)(b*512+m))*64 + chunk];
  float sx = c0.x, sy = c0.y;
  for (int i = 0; i < 64; ++i, ++row){
    unsigned av = aint[row*512 + m];
    unsigned uv = uint_[row*512 + m];
    float ar = b2f((u16)av), ai = b2f((u16)(av>>16));
    float ur = b2f((u16)uv), ui = b2f((u16)(uv>>16));
    float tx = sx + ur, ty = sy + ui;
    sx = ar*tx - ai*ty; sy = ar*ty + ai*tx;
    sout[row*512 + m] = (unsigned)f2b(sx) | ((unsigned)f2b(sy) << 16);
  }
}

// ---------------- host ----------------
extern "C" void kernel_launch(void* const* d_in, const int* in_sizes, int n_in,
                              void* d_out, int out_size, void* d_ws, size_t ws_size,
                              hipStream_t stream){
  (void)in_sizes; (void)n_in; (void)out_size; (void)ws_size;
  const float* x   = (const float*)d_in[0];
  const float* wa  = (const float*)d_in[1];
  const float* wx  = (const float*)d_in[2];
  const float* wo  = (const float*)d_in[3];
  const float* vr  = (const float*)d_in[4];
  const float* vi  = (const float*)d_in[5];
  const float* lhr = (const float*)d_in[6];
  const float* lhi = (const float*)d_in[7];

  char* ws = (char*)d_ws;
  const size_t SB = 16384ull*1024*2;      // 33.5 MB
  const size_t HB = SB/2;
  u16* Xb    = (u16*)(ws);                // later reused as U
  unsigned* AINT = (unsigned*)(ws + SB);  // interleaved a ; first half later HRE
  u16* XROLL = (u16*)(ws + 2*SB);         // later reused as S
  u16* XCRE  = (u16*)(ws + 3*SB);
  char* p = ws + 3*SB + HB;
  u16* WAb   = (u16*)p; p += 2097152;
  u16* WXb   = (u16*)p; p += 2097152;
  u16* MINV  = (u16*)p; p += 2097152;
  u16* MV4   = (u16*)p; p += 1048576;
  u16* WOUTb = (u16*)p; p += 1048576;
  float2* AUG   = (float2*)p; p += 4194304;
  float2* PROWA = (float2*)p; p += 262144;
  float2* PROWB = (float2*)p; p += 262144;
  float2* BINV  = (float2*)p; p += 8192;
  float4* AGG   = (float4*)p; p += 2048ull*64*16;
  float2* CARRY = (float2*)p; p += 2048ull*64*8;
  u16* U   = Xb;
  u16* S   = XROLL;
  u16* HRE = (u16*)AINT;

  cast_f32_bf16<<<2048,256,0,stream>>>(x,  Xb,    16777216/4);
  cast_f32_bf16<<<512, 256,0,stream>>>(wa, WAb,   1048576/4);
  cast_f32_bf16<<<512, 256,0,stream>>>(wx, WXb,   1048576/4);
  cast_f32_bf16<<<256, 256,0,stream>>>(wo, WOUTb, 524288/4);

  inv_init<<<2048,256,0,stream>>>(vr, vi, AUG, PROWA);
  float2* pr = PROWA; float2* prn = PROWB;
  for (int bs = 0; bs < 512; bs += 32){
    inv_panel<<<1,256,0,stream>>>(AUG, bs, BINV);
    inv_update<<<dim3((992-bs)/32, 4),256,0,stream>>>(AUG, bs, pr, prn, BINV);
    float2* t = pr; pr = prn; prn = t;
  }
  build_minv<<<4096,256,0,stream>>>(AUG, MINV);
  build_mv4<<<2048,256,0,stream>>>(vr, vi, MV4);

  gemm128<EPI_A><<<dim3(128,8),256,0,stream>>>(Xb, WAb, 16384,1024,1024, nullptr, (void*)AINT, nullptr);
  gemm128<EPI_X><<<dim3(128,8),256,0,stream>>>(Xb, WXb, 16384,1024,1024, nullptr, (void*)XCRE, (void*)XROLL);
  fill_h0<<<16,256,0,stream>>>(lhr, lhi, XROLL);
  gemm128<EPI_BF16><<<dim3(128,8),256,0,stream>>>(XROLL, MINV, 16384,1024,1024, (void*)U, nullptr, nullptr);

  scan_p1<<<512,256,0,stream>>>((const unsigned*)AINT, (const unsigned*)U, AGG);
  scan_p2<<<8,256,0,stream>>>(AGG, CARRY);
  scan_p3<<<512,256,0,stream>>>((const unsigned*)AINT, (const unsigned*)U, CARRY, (unsigned*)S);

  gemm128<EPI_ADDXC><<<dim3(128,4),256,0,stream>>>(S, MV4, 16384,512,1024, (void*)HRE, (void*)XCRE, nullptr);
  gemm128<EPI_OUTF32><<<dim3(128,8),256,0,stream>>>(HRE, WOUTb, 16384,1024,512, d_out, nullptr, nullptr);
}

// Round 3
// 1390.185 us; speedup vs baseline: 1.4774x; 1.0525x over previous
//
#include <hip/hip_runtime.h>

typedef unsigned short u16;
typedef short bf16x8 __attribute__((ext_vector_type(8)));
typedef float f32x4 __attribute__((ext_vector_type(4)));

typedef const __attribute__((address_space(1))) void* gaddr_t;
typedef __attribute__((address_space(3))) void* laddr_t;

__device__ __forceinline__ u16 f2b(float f){
  unsigned u = __float_as_uint(f);
  u = (u + 0x7fffu + ((u >> 16) & 1u)) >> 16;
  return (u16)u;
}
__device__ __forceinline__ float b2f(u16 h){
  return __uint_as_float(((unsigned)h) << 16);
}

// ---------------- merged cast ----------------
__global__ void cast_all(const float* __restrict__ x, const float* __restrict__ wa,
                         const float* __restrict__ wx, const float* __restrict__ wo,
                         u16* __restrict__ Xb, u16* __restrict__ WAb,
                         u16* __restrict__ WXb, u16* __restrict__ WOb){
  int i = blockIdx.x*blockDim.x + threadIdx.x;
  int st = gridDim.x*blockDim.x;
  // totals in float4 units: x 4194304, wa 262144, wx 262144, wo 131072
  for (int idx = i; idx < 4849664; idx += st){
    const float* s; u16* d; int o;
    if (idx < 4194304){ s = x; d = Xb; o = idx; }
    else if (idx < 4456448){ s = wa; d = WAb; o = idx - 4194304; }
    else if (idx < 4718592){ s = wx; d = WXb; o = idx - 4456448; }
    else { s = wo; d = WOb; o = idx - 4718592; }
    float4 v = ((const float4*)s)[o];
    ushort4 r; r.x=f2b(v.x); r.y=f2b(v.y); r.z=f2b(v.z); r.w=f2b(v.w);
    ((ushort4*)d)[o] = r;
  }
}

// ---------------- inversion: blocked Gauss-Jordan on [V | I] ----------------
__global__ void inv_init(const float* __restrict__ vr, const float* __restrict__ vi,
                         float2* __restrict__ aug, float2* __restrict__ prow){
  int idx = blockIdx.x*256 + threadIdx.x;   // 512*1024
  int r = idx >> 10, c = idx & 1023;
  float2 v;
  if (c < 512) v = make_float2(vr[r*512+c], vi[r*512+c]);
  else         v = make_float2((c-512)==r ? 1.f : 0.f, 0.f);
  aug[idx] = v;
  if (r < 32 && c >= 32) prow[idx] = v;     // pivot-row copy for step bs=0
}

// 32x32 complex GJ inverse, single wave, fully in registers.
// lane l holds augmented column l (l<32: block col; l>=32: identity col l-32).
__global__ __launch_bounds__(64) void inv_panel(const float2* __restrict__ aug, int bs,
                                                float2* __restrict__ binv){
  const int lane = threadIdx.x;
  float tx[32], ty[32];
  #pragma unroll
  for (int r = 0; r < 32; ++r){
    if (lane < 32){
      float2 v = aug[(size_t)(bs+r)*1024 + bs + lane];
      tx[r] = v.x; ty[r] = v.y;
    } else {
      tx[r] = ((lane-32)==r) ? 1.f : 0.f; ty[r] = 0.f;
    }
  }
  #pragma unroll
  for (int k = 0; k < 32; ++k){
    float px = __shfl(tx[k], k), py = __shfl(ty[k], k);
    float dkk = px*px + py*py;
    if (dkk < 1e-8f){                      // uniform branch; rare safety path
      float bm = -1.f; int bp = k;
      #pragma unroll
      for (int r = k; r < 32; ++r){
        float m2 = tx[r]*tx[r] + ty[r]*ty[r];
        if (m2 > bm){ bm = m2; bp = r; }
      }
      int p = __shfl(bp, k);
      if (p != k){
        float okx = tx[k], oky = ty[k];
        float spx = okx, spy = oky;
        #pragma unroll
        for (int r = 1; r < 32; ++r){ if (r > k && r == p){ spx = tx[r]; spy = ty[r]; } }
        #pragma unroll
        for (int r = 1; r < 32; ++r){ if (r > k && r == p){ tx[r] = okx; ty[r] = oky; } }
        tx[k] = spx; ty[k] = spy;
        px = __shfl(spx, k); py = __shfl(spy, k);
        dkk = px*px + py*py;
      }
    }
    float dinv = 1.f / dkk;
    float pvx = px*dinv, pvy = -py*dinv;   // 1/pivot
    float nx = tx[k]*pvx - ty[k]*pvy;
    float ny = tx[k]*pvy + ty[k]*pvx;
    tx[k] = nx; ty[k] = ny;
    #pragma unroll
    for (int r = 0; r < 32; ++r){
      if (r == k) continue;
      float fx = __shfl(tx[r], k), fy = __shfl(ty[r], k);
      tx[r] -= fx*nx - fy*ny;
      ty[r] -= fx*ny + fy*nx;
    }
  }
  if (lane >= 32){
    #pragma unroll
    for (int r = 0; r < 32; ++r)
      binv[r*32 + (lane-32)] = make_float2(tx[r], ty[r]);
  }
}

// trailing update: piv rows <- Binv*Prow ; others -= P * (Binv*Prow)
__global__ __launch_bounds__(256) void inv_update(float2* __restrict__ aug, int bs,
    const float2* __restrict__ prow, float2* __restrict__ prow_next,
    const float2* __restrict__ binv){
  __shared__ float2 Bi[32][33];
  __shared__ float2 Pr[32][33];
  __shared__ float2 T1[32][33];
  __shared__ float2 Pc[128][33];
  const int tid = threadIdx.x;
  const int c0 = bs + 32 + blockIdx.x*32;
  const int r0 = blockIdx.y*128;
  for (int idx = tid; idx < 1024; idx += 256){
    Bi[idx>>5][idx&31] = binv[idx];
    Pr[idx>>5][idx&31] = prow[(size_t)(idx>>5)*1024 + c0 + (idx&31)];
  }
  for (int idx = tid; idx < 128*32; idx += 256){
    int rr = idx>>5, j = idx&31;
    Pc[rr][j] = aug[(size_t)(r0+rr)*1024 + bs + j];
  }
  __syncthreads();
  for (int idx = tid; idx < 1024; idx += 256){
    int j = idx>>5, cc2 = idx&31;
    float2 acc = make_float2(0.f, 0.f);
    #pragma unroll
    for (int kk = 0; kk < 32; ++kk){
      float2 bv = Bi[j][kk], sv = Pr[kk][cc2];
      acc.x += bv.x*sv.x - bv.y*sv.y;
      acc.y += bv.x*sv.y + bv.y*sv.x;
    }
    T1[j][cc2] = acc;
  }
  __syncthreads();
  const int cc = tid & 31;
  float2 t1c[32];
  #pragma unroll
  for (int j = 0; j < 32; ++j) t1c[j] = T1[j][cc];
  #pragma unroll 4
  for (int i = 0; i < 16; ++i){
    int idx = tid + i*256;
    int rr = idx>>5;
    int r = r0+rr, c = c0+cc;
    float2 nv;
    if (r >= bs && r < bs+32){
      nv = T1[r-bs][cc];
    } else {
      nv = aug[(size_t)r*1024 + c];
      #pragma unroll
      for (int j = 0; j < 32; ++j){
        float2 pq = Pc[rr][j], t = t1c[j];
        nv.x -= pq.x*t.x - pq.y*t.y;
        nv.y -= pq.x*t.y + pq.y*t.x;
      }
    }
    aug[(size_t)r*1024 + c] = nv;
    int rn = r - (bs+32);
    if (rn >= 0 && rn < 32) prow_next[(size_t)rn*1024 + c] = nv;
  }
}

// ---------------- small builds ----------------
__global__ void build_minv(const float2* __restrict__ aug, u16* __restrict__ Mi){
  int idx = blockIdx.x*256 + threadIdx.x;     // 1024*1024
  int row = idx >> 10, col = idx & 1023;
  int m = row >> 1, irow = row & 1;
  int k = col & 511, icol = col >> 9;
  float2 a = aug[(size_t)m*1024 + 512 + k];   // Vinv[m][k]
  float v;
  if (!irow) v = icol ? -a.y : a.x;
  else       v = icol ?  a.x : a.y;
  Mi[idx] = f2b(v);
}
__global__ void build_mv4(const float* __restrict__ vr, const float* __restrict__ vi,
                          u16* __restrict__ Mv){
  int idx = blockIdx.x*256 + threadIdx.x;     // 512*1024
  int m = idx >> 10, col = idx & 1023;
  int n = col >> 1;
  float v = (col & 1) ? -vi[m*512+n] : vr[m*512+n];
  Mv[idx] = f2b(v);
}
__global__ void fill_h0(const float* __restrict__ lhr, const float* __restrict__ lhi,
                        u16* __restrict__ xroll){
  int idx = blockIdx.x*256 + threadIdx.x;     // 4*1024
  int b = idx >> 10, c = idx & 1023;
  float v = (c < 512) ? lhr[c] : lhi[c-512];
  xroll[(size_t)b*4096*1024 + c] = f2b(v);
}

// ---------------- GEMM: 256x256 tile, 8-wave, BK=32, 4-deep LDS ring ----------------
// counted vmcnt (never 0 in steady state), granule-XOR LDS swizzle, setprio on MFMA.
enum { EPI_BF16 = 0, EPI_A = 1, EPI_X = 2, EPI_ADDXC = 3, EPI_OUTF32 = 4 };

#define MFMA_BF16(a,b,c) __builtin_amdgcn_mfma_f32_16x16x32_bf16(a,b,c,0,0,0)

template<int EPI>
__global__ __launch_bounds__(512, 2) void gemm256(
    const u16* __restrict__ A, const u16* __restrict__ B,
    int K, int NT, int N,
    void* __restrict__ C, void* __restrict__ aux0, void* __restrict__ aux1)
{
  extern __shared__ u16 LDS[];   // 131072 u16? no: 65536 u16 = 128KB
  const int tid = threadIdx.x;
  const int w = tid >> 6, lane = tid & 63;
  const int wm = w >> 2, wn = w & 3;
  const int fr = lane & 15, kg = lane >> 4;

  // bijective XCD swizzle (gridDim.x % 8 == 0), bx fastest (nbx = 64)
  const int cpx = gridDim.x >> 3;
  const int bid = blockIdx.x;
  const int swz = (bid & 7)*cpx + (bid >> 3);
  const int bx = swz & 63, by = swz >> 6;
  const size_t arow0 = (size_t)bx * 256;
  const int bcol0 = by * 256;

  // staging (global -> LDS DMA), pre-swizzled source, linear dest
  const int rL = w*16 + (lane >> 2);                  // 0..127 row within half-tile
  const int glog = (lane & 3) ^ ((lane >> 3) & 3);    // logical granule
  const u16* Asrc = A + (arow0 + rL)*(size_t)K + glog*8;
  const u16* Bsrc = B + ((size_t)(bcol0 + rL))*K + glog*8;
  const size_t KH = (size_t)128 * K;                  // half stride (rows)
  const int sdst = w*512;                             // + buf*8192 + h*4096 (+lane*8 by HW)

  // fragment read offsets (u16 units), swizzled
  const int goff = (kg ^ ((fr >> 1) & 3)) * 8;
  const int aro = wm*4096 + fr*32 + goff;                              // + buf*8192 + M*512
  const int bro = 32768 + (wn>>1)*4096 + (wn&1)*2048 + fr*32 + goff;   // + buf*8192 + Np*512

  f32x4 acc[8][4] = {};
  bf16x8 bfr[4];

  auto STG_A = [&](int kt){
    int bo = (kt & 3)*8192;
    #pragma unroll
    for (int h = 0; h < 2; ++h)
      __builtin_amdgcn_global_load_lds((gaddr_t)(Asrc + h*KH + kt*32),
          (laddr_t)(LDS + bo + h*4096 + sdst), 16, 0, 0);
  };
  auto STG_B = [&](int kt){
    int bo = 32768 + (kt & 3)*8192;
    #pragma unroll
    for (int h = 0; h < 2; ++h)
      __builtin_amdgcn_global_load_lds((gaddr_t)(Bsrc + h*KH + kt*32),
          (laddr_t)(LDS + bo + h*4096 + sdst), 16, 0, 0);
  };

  auto TILE = [&](int kt, int stg, int wait){
    const int ab = (kt & 3)*8192 + aro;
    const int bb = (kt & 3)*8192 + bro;
    bf16x8 af[4];
    // ---- phase A: M = 0..3 ----
    #pragma unroll
    for (int m = 0; m < 4; ++m) af[m] = *(const bf16x8*)&LDS[ab + m*512];
    #pragma unroll
    for (int n = 0; n < 4; ++n) bfr[n] = *(const bf16x8*)&LDS[bb + n*512];
    if (stg) STG_A(kt + 3);
    __builtin_amdgcn_s_barrier();
    __builtin_amdgcn_s_setprio(1);
    #pragma unroll
    for (int m = 0; m < 4; ++m)
      #pragma unroll
      for (int n = 0; n < 4; ++n)
        acc[m][n] = MFMA_BF16(af[m], bfr[n], acc[m][n]);
    __builtin_amdgcn_s_setprio(0);
    __builtin_amdgcn_s_barrier();
    // ---- phase B: M = 4..7 ----
    #pragma unroll
    for (int m = 0; m < 4; ++m) af[m] = *(const bf16x8*)&LDS[ab + (m+4)*512];
    if (stg) STG_B(kt + 3);
    __builtin_amdgcn_s_barrier();
    __builtin_amdgcn_s_setprio(1);
    #pragma unroll
    for (int m = 0; m < 4; ++m)
      #pragma unroll
      for (int n = 0; n < 4; ++n)
        acc[m+4][n] = MFMA_BF16(af[m], bfr[n], acc[m+4][n]);
    __builtin_amdgcn_s_setprio(0);
    if (wait == 2){ asm volatile("s_waitcnt vmcnt(8)" ::: "memory"); }
    else if (wait == 1){ asm volatile("s_waitcnt vmcnt(4)" ::: "memory"); }
    else if (wait == 0){ asm volatile("s_waitcnt vmcnt(0)" ::: "memory"); }
    __builtin_amdgcn_sched_barrier(0);
    __builtin_amdgcn_s_barrier();
  };

  // prologue: stage tiles 0,1,2 (12 loads/wave); wait until tile 0 landed (8 left)
  STG_A(0); STG_B(0); STG_A(1); STG_B(1); STG_A(2); STG_B(2);
  asm volatile("s_waitcnt vmcnt(8)" ::: "memory");
  __builtin_amdgcn_sched_barrier(0);
  __builtin_amdgcn_s_barrier();

  #pragma unroll 1
  for (int kt = 0; kt < NT - 3; ++kt) TILE(kt, 1, 2);
  TILE(NT-3, 0, 1);
  TILE(NT-2, 0, 0);
  TILE(NT-1, 0, -1);

  // ---- epilogue ----
  const int rbase = wm*128 + (lane >> 4)*4;
  const int cbase = wn*64 + fr;
  #pragma unroll
  for (int M = 0; M < 8; ++M){
    #pragma unroll
    for (int Np = 0; Np < 4; ++Np){
      #pragma unroll
      for (int j = 0; j < 4; ++j){
        float v = acc[M][Np][j];
        size_t gr = arow0 + rbase + M*16 + j;
        int gc = bcol0 + cbase + Np*16;
        if constexpr (EPI == EPI_BF16){
          ((u16*)C)[gr*(size_t)N + gc] = f2b(v);
        } else if constexpr (EPI == EPI_OUTF32){
          ((float*)C)[gr*(size_t)N + gc] = v;
        } else if constexpr (EPI == EPI_ADDXC){
          float xc = b2f(((const u16*)aux0)[gr*512 + gc]);
          ((u16*)C)[gr*512 + gc] = f2b(v + xc);
        } else {
          float pv = __shfl_xor(v, 1);
          int odd = lane & 1;
          float re = odd ? pv : v;
          float im = odd ? v : pv;
          float m2 = re*re + im*im;
          int mh = gc >> 1;
          if constexpr (EPI == EPI_A){
            float sc = m2 > 0.f ? sqrtf(m2)/(1.f + m2) : 0.f;   // sigmoid(log m) = m/(1+m)
            if (!odd){
              unsigned pk = (unsigned)f2b(re*sc) | ((unsigned)f2b(im*sc) << 16);
              ((unsigned*)aux0)[gr*512 + mh] = pk;              // interleaved complex a
            }
          } else { // EPI_X : xc = x2 * sqrt(m)
            float sc = sqrtf(m2);
            u16 ob = f2b(v * sc);
            if (!odd) ((u16*)aux0)[gr*512 + mh] = ob;           // xc_re
            int t = (int)(gr & 4095);
            if (t != 4095)                                      // x_roll[t+1] = xc[t]
              ((u16*)aux1)[(gr+1)*1024 + (odd ? 512 + mh : mh)] = ob;
          }
        }
      }
    }
  }
}

// ---------------- scan: s_t = a_t*(s_{t-1}+u_t), chunked 3-phase ----------------
__global__ void scan_p1(const unsigned* __restrict__ aint, const unsigned* __restrict__ uint_,
                        float4* __restrict__ agg){
  int idx = blockIdx.x*256 + threadIdx.x;   // 4*64*512 = 131072
  int m = idx & 511, chunk = (idx >> 9) & 63, b = idx >> 15;
  size_t row = (size_t)b*4096 + chunk*64;
  float px=1.f, py=0.f, sx=0.f, sy=0.f;
  for (int i = 0; i < 64; ++i, ++row){
    unsigned av = aint[row*512 + m];
    unsigned uv = uint_[row*512 + m];
    float ar = b2f((u16)av), ai = b2f((u16)(av>>16));
    float ur = b2f((u16)uv), ui = b2f((u16)(uv>>16));
    float tx2 = sx + ur, ty2 = sy + ui;
    sx = ar*tx2 - ai*ty2; sy = ar*ty2 + ai*tx2;
    float np = px*ar - py*ai; py = px*ai + py*ar; px = np;
  }
  agg[((size_t)(b*512+m))*64 + chunk] = make_float4(px,py,sx,sy);
}
__global__ void scan_p2(const float4* __restrict__ agg, float2* __restrict__ carry){
  int seq = blockIdx.x*256 + threadIdx.x;   // 2048
  float sx = 0.f, sy = 0.f;
  for (int c = 0; c < 64; ++c){
    carry[(size_t)seq*64 + c] = make_float2(sx, sy);
    float4 g = agg[(size_t)seq*64 + c];
    float nx = g.x*sx - g.y*sy + g.z;
    sy = g.x*sy + g.y*sx + g.w; sx = nx;
  }
}
__global__ void scan_p3(const unsigned* __restrict__ aint, const unsigned* __restrict__ uint_,
                        const float2* __restrict__ carry, unsigned* __restrict__ sout){
  int idx = blockIdx.x*256 + threadIdx.x;
  int m = idx & 511, chunk = (idx >> 9) & 63, b = idx >> 15;
  size_t row = (size_t)b*4096 + chunk*64;
  float2 c0 = carry[((size_t)(b*512+m))*64 + chunk];
  float sx = c0.x, sy = c0.y;
  for (int i = 0; i < 64; ++i, ++row){
    unsigned av = aint[row*512 + m];
    unsigned uv = uint_[row*512 + m];
    float ar = b2f((u16)av), ai = b2f((u16)(av>>16));
    float ur = b2f((u16)uv), ui = b2f((u16)(uv>>16));
    float tx2 = sx + ur, ty2 = sy + ui;
    sx = ar*tx2 - ai*ty2; sy = ar*ty2 + ai*tx2;
    sout[row*512 + m] = (unsigned)f2b(sx) | ((unsigned)f2b(sy) << 16);
  }
}

// ---------------- host ----------------
extern "C" void kernel_launch(void* const* d_in, const int* in_sizes, int n_in,
                              void* d_out, int out_size, void* d_ws, size_t ws_size,
                              hipStream_t stream){
  (void)in_sizes; (void)n_in; (void)out_size; (void)ws_size;
  const float* x   = (const float*)d_in[0];
  const float* wa  = (const float*)d_in[1];
  const float* wx  = (const float*)d_in[2];
  const float* wo  = (const float*)d_in[3];
  const float* vr  = (const float*)d_in[4];
  const float* vi  = (const float*)d_in[5];
  const float* lhr = (const float*)d_in[6];
  const float* lhi = (const float*)d_in[7];

  char* ws = (char*)d_ws;
  const size_t SB = 16384ull*1024*2;      // 33.5 MB
  const size_t HB = SB/2;
  u16* Xb    = (u16*)(ws);                // later reused as U
  unsigned* AINT = (unsigned*)(ws + SB);  // interleaved a ; later HRE
  u16* XROLL = (u16*)(ws + 2*SB);         // later reused as S
  u16* XCRE  = (u16*)(ws + 3*SB);
  char* p = ws + 3*SB + HB;
  u16* WAb   = (u16*)p; p += 2097152;
  u16* WXb   = (u16*)p; p += 2097152;
  u16* MINV  = (u16*)p; p += 2097152;
  u16* MV4   = (u16*)p; p += 1048576;
  u16* WOUTb = (u16*)p; p += 1048576;
  float2* AUG   = (float2*)p; p += 4194304;
  float2* PROWA = (float2*)p; p += 262144;
  float2* PROWB = (float2*)p; p += 262144;
  float2* BINV  = (float2*)p; p += 8192;
  float4* AGG   = (float4*)p; p += 2048ull*64*16;
  float2* CARRY = (float2*)p; p += 2048ull*64*8;
  u16* U   = Xb;
  u16* S   = XROLL;
  u16* HRE = (u16*)AINT;

  cast_all<<<2048,256,0,stream>>>(x, wa, wx, wo, Xb, WAb, WXb, WOUTb);

  inv_init<<<2048,256,0,stream>>>(vr, vi, AUG, PROWA);
  float2* pr = PROWA; float2* prn = PROWB;
  for (int bs = 0; bs < 512; bs += 32){
    inv_panel<<<1,64,0,stream>>>(AUG, bs, BINV);
    inv_update<<<dim3((992-bs)/32, 4),256,0,stream>>>(AUG, bs, pr, prn, BINV);
    float2* t = pr; pr = prn; prn = t;
  }
  build_minv<<<4096,256,0,stream>>>(AUG, MINV);
  build_mv4<<<2048,256,0,stream>>>(vr, vi, MV4);

  const size_t GLDS = 131072;
  gemm256<EPI_A><<<256,512,GLDS,stream>>>(Xb, WAb, 1024, 32, 1024, nullptr, (void*)AINT, nullptr);
  gemm256<EPI_X><<<256,512,GLDS,stream>>>(Xb, WXb, 1024, 32, 1024, nullptr, (void*)XCRE, (void*)XROLL);
  fill_h0<<<16,256,0,stream>>>(lhr, lhi, XROLL);
  gemm256<EPI_BF16><<<256,512,GLDS,stream>>>(XROLL, MINV, 1024, 32, 1024, (void*)U, nullptr, nullptr);

  scan_p1<<<512,256,0,stream>>>((const unsigned*)AINT, (const unsigned*)U, AGG);
  scan_p2<<<8,256,0,stream>>>(AGG, CARRY);
  scan_p3<<<512,256,0,stream>>>((const unsigned*)AINT, (const unsigned*)U, CARRY, (unsigned*)S);

  gemm256<EPI_ADDXC><<<128,512,GLDS,stream>>>(S, MV4, 1024, 32, 512, (void*)HRE, (void*)XCRE, nullptr);
  gemm256<EPI_OUTF32><<<256,512,GLDS,stream>>>(HRE, WOUTb, 512, 16, 1024, d_out, nullptr, nullptr);
}

// Round 4
// 1300.173 us; speedup vs baseline: 1.5797x; 1.0692x over previous
//
#include <hip/hip_runtime.h>

typedef unsigned short u16;
typedef short bf16x8 __attribute__((ext_vector_type(8)));
typedef float f32x4 __attribute__((ext_vector_type(4)));

typedef const __attribute__((address_space(1))) void* gaddr_t;
typedef __attribute__((address_space(3))) void* laddr_t;

__device__ __forceinline__ u16 f2b(float f){
  unsigned u = __float_as_uint(f);
  u = (u + 0x7fffu + ((u >> 16) & 1u)) >> 16;
  return (u16)u;
}
__device__ __forceinline__ float b2f(u16 h){
  return __uint_as_float(((unsigned)h) << 16);
}
__device__ __forceinline__ float2 cmul(float2 a, float2 b){
  return make_float2(a.x*b.x - a.y*b.y, a.x*b.y + a.y*b.x);
}

// ---------------- merged cast ----------------
// WABb = [WA(1024 rows); WX(1024 rows)] contiguous, each row K=1024
__global__ void cast_all(const float* __restrict__ x, const float* __restrict__ wa,
                         const float* __restrict__ wx, const float* __restrict__ wo,
                         u16* __restrict__ Xb, u16* __restrict__ WABb,
                         u16* __restrict__ WOb){
  int i = blockIdx.x*blockDim.x + threadIdx.x;
  int st = gridDim.x*blockDim.x;
  for (int idx = i; idx < 4849664; idx += st){
    const float* s; u16* d; int o;
    if (idx < 4194304){ s = x; d = Xb; o = idx; }
    else if (idx < 4456448){ s = wa; d = WABb; o = idx - 4194304; }
    else if (idx < 4718592){ s = wx; d = WABb + 1048576; o = idx - 4456448; }
    else { s = wo; d = WOb; o = idx - 4718592; }
    float4 v = ((const float4*)s)[o];
    ushort4 r; r.x=f2b(v.x); r.y=f2b(v.y); r.z=f2b(v.z); r.w=f2b(v.w);
    ((ushort4*)d)[o] = r;
  }
}

// ---------------- inversion: blocked Gauss-Jordan on [V | I] ----------------
__global__ void inv_init(const float* __restrict__ vr, const float* __restrict__ vi,
                         float2* __restrict__ aug, float2* __restrict__ prow){
  int idx = blockIdx.x*256 + threadIdx.x;   // 512*1024
  int r = idx >> 10, c = idx & 1023;
  float2 v;
  if (c < 512) v = make_float2(vr[r*512+c], vi[r*512+c]);
  else         v = make_float2((c-512)==r ? 1.f : 0.f, 0.f);
  aug[idx] = v;
  if (r < 32 && c >= 32) prow[idx] = v;     // pivot-row copy for step bs=0
}

// 32x32 complex GJ with in-block partial pivoting; augmented [L | R], 256 threads.
__device__ __forceinline__ void gj32(float2 (&L)[32][33], float2 (&R)[32][33],
                                     float2* fcol, int tid){
  for (int k = 0; k < 32; ++k){
    if (tid < 64){
      int lane = tid;
      float2 colv = make_float2(0.f, 0.f);
      float mag = -1.f;
      if (lane < 32){
        colv = L[lane][k];
        if (lane >= k) mag = colv.x*colv.x + colv.y*colv.y;
      }
      int best = lane;
      #pragma unroll
      for (int off = 1; off < 32; off <<= 1){
        float om = __shfl_xor(mag, off);
        int ob  = __shfl_xor(best, off);
        if (om > mag || (om == mag && ob < best)){ mag = om; best = ob; }
      }
      int p = __shfl(best, 0);
      float pvx = __shfl(colv.x, p), pvy = __shfl(colv.y, p);
      float dinv = 1.f / (pvx*pvx + pvy*pvy);
      float2 pinv = make_float2(pvx*dinv, -pvy*dinv);
      float2 rk = (lane < 32) ? L[k][lane] : R[k][lane-32];
      float2 rp = (lane < 32) ? L[p][lane] : R[p][lane-32];
      float2 nk = cmul(rp, pinv);
      if (lane < 32) L[k][lane] = nk; else R[k][lane-32] = nk;
      if (p != k){ if (lane < 32) L[p][lane] = rk; else R[p][lane-32] = rk; }
      if (lane < 32){
        float2 f = colv;
        float okx = __shfl(colv.x, k), oky = __shfl(colv.y, k);
        if (lane == p){ f.x = okx; f.y = oky; }
        fcol[lane] = f;
      }
    }
    __syncthreads();
    #pragma unroll
    for (int i = 0; i < 8; ++i){
      int idx = tid + i*256;
      int r = idx >> 6, c = idx & 63;
      if (r != k){
        float2 f = fcol[r];
        float2 nk = (c < 32) ? L[k][c] : R[k][c-32];
        float2 cell = (c < 32) ? L[r][c] : R[r][c-32];
        cell.x -= f.x*nk.x - f.y*nk.y;
        cell.y -= f.x*nk.y + f.y*nk.x;
        if (c < 32) L[r][c] = cell; else R[r][c-32] = cell;
      }
    }
    __syncthreads();
  }
}

__global__ __launch_bounds__(256) void inv_panel0(const float2* __restrict__ aug,
                                                  float2* __restrict__ binv){
  __shared__ float2 L[32][33];
  __shared__ float2 R[32][33];
  __shared__ float2 fcol[32];
  const int tid = threadIdx.x;
  for (int i = tid; i < 1024; i += 256){
    int r = i >> 5, c = i & 31;
    L[r][c] = aug[(size_t)r*1024 + c];
    R[r][c] = make_float2((r==c) ? 1.f : 0.f, 0.f);
  }
  __syncthreads();
  gj32(L, R, fcol, tid);
  for (int i = tid; i < 1024; i += 256) binv[i] = R[i>>5][i&31];
}

// trailing update: piv rows <- Binv*Prow ; others -= P * (Binv*Prow).
// The (bx==0, by==(bs+32)>>7) block additionally inverts the next 32x32 diagonal
// block (which it just computed) and writes binv_out for the next step.
__global__ __launch_bounds__(256) void inv_update(float2* __restrict__ aug, int bs,
    const float2* __restrict__ prow, float2* __restrict__ prow_next,
    const float2* __restrict__ binv_in, float2* __restrict__ binv_out, int do_panel){
  __shared__ float2 Bi[32][33];
  __shared__ float2 Pr[32][33];
  __shared__ float2 T1[32][33];
  __shared__ float2 Pc[128][33];
  __shared__ float2 fcol[32];
  const int tid = threadIdx.x;
  const int c0 = bs + 32 + blockIdx.x*32;
  const int r0 = blockIdx.y*128;
  const bool panel = do_panel && (blockIdx.x == 0) && ((int)blockIdx.y == ((bs+32) >> 7));
  for (int idx = tid; idx < 1024; idx += 256){
    Bi[idx>>5][idx&31] = binv_in[idx];
    Pr[idx>>5][idx&31] = prow[(size_t)(idx>>5)*1024 + c0 + (idx&31)];
  }
  for (int idx = tid; idx < 128*32; idx += 256){
    int rr = idx>>5, j = idx&31;
    Pc[rr][j] = aug[(size_t)(r0+rr)*1024 + bs + j];
  }
  __syncthreads();
  for (int idx = tid; idx < 1024; idx += 256){
    int j = idx>>5, cc2 = idx&31;
    float2 acc = make_float2(0.f, 0.f);
    #pragma unroll
    for (int kk = 0; kk < 32; ++kk){
      float2 bv = Bi[j][kk], sv = Pr[kk][cc2];
      acc.x += bv.x*sv.x - bv.y*sv.y;
      acc.y += bv.x*sv.y + bv.y*sv.x;
    }
    T1[j][cc2] = acc;
  }
  __syncthreads();
  const int cc = tid & 31;
  float2 t1c[32];
  #pragma unroll
  for (int j = 0; j < 32; ++j) t1c[j] = T1[j][cc];
  __syncthreads();
  #pragma unroll 4
  for (int i = 0; i < 16; ++i){
    int idx = tid + i*256;
    int rr = idx>>5;
    int r = r0+rr, c = c0+cc;
    float2 nv;
    if (r >= bs && r < bs+32){
      nv = T1[r-bs][cc];
    } else {
      nv = aug[(size_t)r*1024 + c];
      #pragma unroll
      for (int j = 0; j < 32; ++j){
        float2 pq = Pc[rr][j], t = t1c[j];
        nv.x -= pq.x*t.x - pq.y*t.y;
        nv.y -= pq.x*t.y + pq.y*t.x;
      }
    }
    aug[(size_t)r*1024 + c] = nv;
    int rn = r - (bs+32);
    if (rn >= 0 && rn < 32){
      prow_next[(size_t)rn*1024 + c] = nv;
      if (panel) Bi[rn][cc] = nv;        // stash next diagonal block (cols c0..c0+31)
    }
  }
  if (panel){
    __syncthreads();
    for (int i = tid; i < 1024; i += 256){
      int r = i>>5, c = i&31;
      Pr[r][c] = make_float2((r==c) ? 1.f : 0.f, 0.f);
    }
    __syncthreads();
    gj32(Bi, Pr, fcol, tid);
    for (int i = tid; i < 1024; i += 256) binv_out[i] = Pr[i>>5][i&31];
  }
}

// ---------------- small builds ----------------
__global__ void build_minv(const float2* __restrict__ aug, u16* __restrict__ Mi){
  int idx = blockIdx.x*256 + threadIdx.x;     // 1024*1024
  int row = idx >> 10, col = idx & 1023;
  int m = row >> 1, irow = row & 1;
  int k = col & 511, icol = col >> 9;
  float2 a = aug[(size_t)m*1024 + 512 + k];   // Vinv[m][k]
  float v;
  if (!irow) v = icol ? -a.y : a.x;
  else       v = icol ?  a.x : a.y;
  Mi[idx] = f2b(v);
}
__global__ void build_mv4(const float* __restrict__ vr, const float* __restrict__ vi,
                          u16* __restrict__ Mv){
  int idx = blockIdx.x*256 + threadIdx.x;     // 512*1024
  int m = idx >> 10, col = idx & 1023;
  int n = col >> 1;
  float v = (col & 1) ? -vi[m*512+n] : vr[m*512+n];
  Mv[idx] = f2b(v);
}
__global__ void fill_h0(const float* __restrict__ lhr, const float* __restrict__ lhi,
                        u16* __restrict__ xroll){
  int idx = blockIdx.x*256 + threadIdx.x;     // 4*1024
  int b = idx >> 10, c = idx & 1023;
  float v = (c < 512) ? lhr[c] : lhi[c-512];
  xroll[(size_t)b*4096*1024 + c] = f2b(v);
}

// ---------------- GEMM: 256x256 tile, 8-wave, BK=32, 4-deep LDS ring ----------------
enum { EPI_BF16 = 0, EPI_ADDXC = 3, EPI_OUTF32 = 4, EPI_AX = 5 };

#define MFMA_BF16(a,b,c) __builtin_amdgcn_mfma_f32_16x16x32_bf16(a,b,c,0,0,0)

template<int EPI>
__global__ __launch_bounds__(512, 2) void gemm256(
    const u16* __restrict__ A, const u16* __restrict__ B,
    int K, int NT, int N, int byShift,
    void* __restrict__ C, void* __restrict__ aux0, void* __restrict__ aux1,
    void* __restrict__ aux2)
{
  extern __shared__ u16 LDS[];   // 65536 u16 = 128 KB
  const int tid = threadIdx.x;
  const int w = tid >> 6, lane = tid & 63;
  const int wm = w >> 2, wn = w & 3;
  const int fr = lane & 15, kg = lane >> 4;

  // bijective XCD swizzle; by (N-panel) fastest so same-A blocks co-run per XCD
  const int cpx = gridDim.x >> 3;
  const int bid = blockIdx.x;
  const int swz = (bid & 7)*cpx + (bid >> 3);
  const int by = swz & ((1 << byShift) - 1), bx = swz >> byShift;
  const size_t arow0 = (size_t)bx * 256;
  const int bcol0 = by * 256;

  // staging (global -> LDS DMA), pre-swizzled source, linear dest
  const int rL = w*16 + (lane >> 2);                  // 0..127 row within half
  const int glog = (lane & 3) ^ ((lane >> 3) & 3);    // logical granule
  const u16* Asrc = A + (arow0 + rL)*(size_t)K + glog*8;
  const u16* Bsrc = B + ((size_t)(bcol0 + rL))*K + glog*8;
  const size_t KH = (size_t)128 * K;
  const int sdst = w*512;

  // fragment read offsets (u16 units), swizzled
  const int goff = (kg ^ ((fr >> 1) & 3)) * 8;
  const int aro = wm*4096 + fr*32 + goff;
  const int bro = 32768 + (wn>>1)*4096 + (wn&1)*2048 + fr*32 + goff;

  f32x4 acc[8][4] = {};
  bf16x8 bfr[4];

  auto STG_A = [&](int kt){
    int bo = (kt & 3)*8192;
    #pragma unroll
    for (int h = 0; h < 2; ++h)
      __builtin_amdgcn_global_load_lds((gaddr_t)(Asrc + h*KH + kt*32),
          (laddr_t)(LDS + bo + h*4096 + sdst), 16, 0, 0);
  };
  auto STG_B = [&](int kt){
    int bo = 32768 + (kt & 3)*8192;
    #pragma unroll
    for (int h = 0; h < 2; ++h)
      __builtin_amdgcn_global_load_lds((gaddr_t)(Bsrc + h*KH + kt*32),
          (laddr_t)(LDS + bo + h*4096 + sdst), 16, 0, 0);
  };

  auto TILE = [&](int kt, int stg, int wait){
    const int ab = (kt & 3)*8192 + aro;
    const int bb = (kt & 3)*8192 + bro;
    bf16x8 af[4];
    // ---- phase A: M = 0..3 ----
    #pragma unroll
    for (int m = 0; m < 4; ++m) af[m] = *(const bf16x8*)&LDS[ab + m*512];
    #pragma unroll
    for (int n = 0; n < 4; ++n) bfr[n] = *(const bf16x8*)&LDS[bb + n*512];
    if (stg) STG_A(kt + 3);
    __builtin_amdgcn_s_barrier();
    __builtin_amdgcn_s_setprio(1);
    #pragma unroll
    for (int m = 0; m < 4; ++m)
      #pragma unroll
      for (int n = 0; n < 4; ++n)
        acc[m][n] = MFMA_BF16(af[m], bfr[n], acc[m][n]);
    __builtin_amdgcn_s_setprio(0);
    __builtin_amdgcn_s_barrier();
    // ---- phase B: M = 4..7 ----
    #pragma unroll
    for (int m = 0; m < 4; ++m) af[m] = *(const bf16x8*)&LDS[ab + (m+4)*512];
    if (stg) STG_B(kt + 3);
    __builtin_amdgcn_s_barrier();
    __builtin_amdgcn_s_setprio(1);
    #pragma unroll
    for (int m = 0; m < 4; ++m)
      #pragma unroll
      for (int n = 0; n < 4; ++n)
        acc[m+4][n] = MFMA_BF16(af[m], bfr[n], acc[m+4][n]);
    __builtin_amdgcn_s_setprio(0);
    if (wait == 2){ asm volatile("s_waitcnt vmcnt(8)" ::: "memory"); }
    else if (wait == 1){ asm volatile("s_waitcnt vmcnt(4)" ::: "memory"); }
    else if (wait == 0){ asm volatile("s_waitcnt vmcnt(0)" ::: "memory"); }
    __builtin_amdgcn_sched_barrier(0);
    __builtin_amdgcn_s_barrier();
  };

  // prologue: stage tiles 0,1,2; wait until tile 0 landed (8 left)
  STG_A(0); STG_B(0); STG_A(1); STG_B(1); STG_A(2); STG_B(2);
  asm volatile("s_waitcnt vmcnt(8)" ::: "memory");
  __builtin_amdgcn_sched_barrier(0);
  __builtin_amdgcn_s_barrier();

  #pragma unroll 1
  for (int kt = 0; kt < NT - 3; ++kt) TILE(kt, 1, 2);
  TILE(NT-3, 0, 1);
  TILE(NT-2, 0, 0);
  TILE(NT-1, 0, -1);

  // ---- epilogue ----
  const int rbase = wm*128 + (lane >> 4)*4;
  const int cbase = wn*64 + fr;
  #pragma unroll
  for (int M = 0; M < 8; ++M){
    #pragma unroll
    for (int Np = 0; Np < 4; ++Np){
      #pragma unroll
      for (int j = 0; j < 4; ++j){
        float v = acc[M][Np][j];
        size_t gr = arow0 + rbase + M*16 + j;
        int gc = bcol0 + cbase + Np*16;
        if constexpr (EPI == EPI_BF16){
          ((u16*)C)[gr*(size_t)N + gc] = f2b(v);
        } else if constexpr (EPI == EPI_OUTF32){
          ((float*)C)[gr*(size_t)N + gc] = v;
        } else if constexpr (EPI == EPI_ADDXC){
          float xc = b2f(((const u16*)aux0)[gr*512 + gc]);
          ((u16*)C)[gr*512 + gc] = f2b(v + xc);
        } else { // EPI_AX
          float pv = __shfl_xor(v, 1);
          int odd = lane & 1;
          float re = odd ? pv : v;
          float im = odd ? v : pv;
          float m2 = re*re + im*im;
          if (gc < 1024){
            int mh = gc >> 1;
            float sc = m2 > 0.f ? sqrtf(m2)/(1.f + m2) : 0.f;  // sigmoid(log m) = m/(1+m)
            if (!odd){
              unsigned pk = (unsigned)f2b(re*sc) | ((unsigned)f2b(im*sc) << 16);
              ((unsigned*)aux0)[gr*512 + mh] = pk;             // interleaved complex a
            }
          } else {
            int mh = (gc - 1024) >> 1;
            float sc = sqrtf(m2);                              // xc = x2 * sqrt(m)
            u16 ob = f2b(v * sc);
            if (!odd) ((u16*)aux1)[gr*512 + mh] = ob;          // xc_re
            int t = (int)(gr & 4095);
            if (t != 4095)                                     // x_roll[t+1] = xc[t]
              ((u16*)aux2)[(gr+1)*1024 + (odd ? 512 + mh : mh)] = ob;
          }
        }
      }
    }
  }
}

// ---------------- scan: s_t = a_t*(s_{t-1}+u_t), chunked 3-phase ----------------
__global__ void scan_p1(const unsigned* __restrict__ aint, const unsigned* __restrict__ uint_,
                        float4* __restrict__ agg){
  int idx = blockIdx.x*256 + threadIdx.x;   // 4*64*512 = 131072
  int m = idx & 511, chunk = (idx >> 9) & 63, b = idx >> 15;
  size_t row = (size_t)b*4096 + chunk*64;
  float px=1.f, py=0.f, sx=0.f, sy=0.f;
  for (int i = 0; i < 64; ++i, ++row){
    unsigned av = aint[row*512 + m];
    unsigned uv = uint_[row*512 + m];
    float ar = b2f((u16)av), ai = b2f((u16)(av>>16));
    float ur = b2f((u16)uv), ui = b2f((u16)(uv>>16));
    float tx2 = sx + ur, ty2 = sy + ui;
    sx = ar*tx2 - ai*ty2; sy = ar*ty2 + ai*tx2;
    float np = px*ar - py*ai; py = px*ai + py*ar; px = np;
  }
  agg[((size_t)(b*512+m))*64 + chunk] = make_float4(px,py,sx,sy);
}
__global__ void scan_p2(const float4* __restrict__ agg, float2* __restrict__ carry){
  int seq = blockIdx.x*256 + threadIdx.x;   // 2048
  float sx = 0.f, sy = 0.f;
  for (int c = 0; c < 64; ++c){
    carry[(size_t)seq*64 + c] = make_float2(sx, sy);
    float4 g = agg[(size_t)seq*64 + c];
    float nx = g.x*sx - g.y*sy + g.z;
    sy = g.x*sy + g.y*sx + g.w; sx = nx;
  }
}
__global__ void scan_p3(const unsigned* __restrict__ aint, const unsigned* __restrict__ uint_,
                        const float2* __restrict__ carry, unsigned* __restrict__ sout){
  int idx = blockIdx.x*256 + threadIdx.x;
  int m = idx & 511, chunk = (idx >> 9) & 63, b = idx >> 15;
  size_t row = (size_t)b*4096 + chunk*64;
  float2 c0 = carry[((size_t)(b*512+m))*64 + chunk];
  float sx = c0.x, sy = c0.y;
  for (int i = 0; i < 64; ++i, ++row){
    unsigned av = aint[row*512 + m];
    unsigned uv = uint_[row*512 + m];
    float ar = b2f((u16)av), ai = b2f((u16)(av>>16));
    float ur = b2f((u16)uv), ui = b2f((u16)(uv>>16));
    float tx2 = sx + ur, ty2 = sy + ui;
    sx = ar*tx2 - ai*ty2; sy = ar*ty2 + ai*tx2;
    sout[row*512 + m] = (unsigned)f2b(sx) | ((unsigned)f2b(sy) << 16);
  }
}

// ---------------- host ----------------
extern "C" void kernel_launch(void* const* d_in, const int* in_sizes, int n_in,
                              void* d_out, int out_size, void* d_ws, size_t ws_size,
                              hipStream_t stream){
  (void)in_sizes; (void)n_in; (void)out_size; (void)ws_size;
  const float* x   = (const float*)d_in[0];
  const float* wa  = (const float*)d_in[1];
  const float* wx  = (const float*)d_in[2];
  const float* wo  = (const float*)d_in[3];
  const float* vr  = (const float*)d_in[4];
  const float* vi  = (const float*)d_in[5];
  const float* lhr = (const float*)d_in[6];
  const float* lhi = (const float*)d_in[7];

  char* ws = (char*)d_ws;
  const size_t SB = 16384ull*1024*2;      // 33.5 MB
  const size_t HB = SB/2;
  u16* Xb    = (u16*)(ws);                // later reused as U
  unsigned* AINT = (unsigned*)(ws + SB);  // interleaved a ; later HRE
  u16* XROLL = (u16*)(ws + 2*SB);         // later reused as S
  u16* XCRE  = (u16*)(ws + 3*SB);
  char* p = ws + 3*SB + HB;
  u16* WABb  = (u16*)p; p += 4194304;     // [WA;WX] 2048x1024 bf16
  u16* MINV  = (u16*)p; p += 2097152;
  u16* MV4   = (u16*)p; p += 1048576;
  u16* WOUTb = (u16*)p; p += 1048576;
  float2* AUG   = (float2*)p; p += 4194304;
  float2* PROWA = (float2*)p; p += 262144;
  float2* PROWB = (float2*)p; p += 262144;
  float2* BINV0 = (float2*)p; p += 8192;
  float2* BINV1 = (float2*)p; p += 8192;
  float4* AGG   = (float4*)p; p += 2048ull*64*16;
  float2* CARRY = (float2*)p; p += 2048ull*64*8;
  u16* U   = Xb;
  u16* S   = XROLL;
  u16* HRE = (u16*)AINT;

  cast_all<<<2048,256,0,stream>>>(x, wa, wx, wo, Xb, WABb, WOUTb);

  inv_init<<<2048,256,0,stream>>>(vr, vi, AUG, PROWA);
  inv_panel0<<<1,256,0,stream>>>(AUG, BINV0);
  float2* pr = PROWA; float2* prn = PROWB;
  for (int bs = 0; bs < 512; bs += 32){
    int step = bs >> 5;
    float2* bin  = (step & 1) ? BINV1 : BINV0;
    float2* bout = (step & 1) ? BINV0 : BINV1;
    inv_update<<<dim3((992-bs)/32, 4),256,0,stream>>>(AUG, bs, pr, prn, bin, bout,
                                                      bs < 480 ? 1 : 0);
    float2* t = pr; pr = prn; prn = t;
  }
  build_minv<<<4096,256,0,stream>>>(AUG, MINV);
  build_mv4<<<2048,256,0,stream>>>(vr, vi, MV4);
  fill_h0<<<16,256,0,stream>>>(lhr, lhi, XROLL);

  const size_t GLDS = 131072;
  // fused gate+input projection: C cols 0..1023 = a2 (gate), 1024..2047 = x2
  gemm256<EPI_AX><<<512,512,GLDS,stream>>>(Xb, WABb, 1024, 32, 2048, 3,
                                           nullptr, (void*)AINT, (void*)XCRE, (void*)XROLL);
  gemm256<EPI_BF16><<<256,512,GLDS,stream>>>(XROLL, MINV, 1024, 32, 1024, 2,
                                             (void*)U, nullptr, nullptr, nullptr);

  scan_p1<<<512,256,0,stream>>>((const unsigned*)AINT, (const unsigned*)U, AGG);
  scan_p2<<<8,256,0,stream>>>(AGG, CARRY);
  scan_p3<<<512,256,0,stream>>>((const unsigned*)AINT, (const unsigned*)U, CARRY, (unsigned*)S);

  gemm256<EPI_ADDXC><<<128,512,GLDS,stream>>>(S, MV4, 1024, 32, 512, 1,
                                              (void*)HRE, (void*)XCRE, nullptr, nullptr);
  gemm256<EPI_OUTF32><<<256,512,GLDS,stream>>>(HRE, WOUTb, 512, 16, 1024, 2,
                                               d_out, nullptr, nullptr, nullptr);
}